// Round 9
// baseline (224.953 us; speedup 1.0000x reference)
//
#include <hip/hip_runtime.h>
#include <stdint.h>
#include <stddef.h>

#define M_DIM 2048
#define N_DIM 4096
#define K_DIM 4352
#define H_DIM 1024
#define X_DIM 2304

// workspace layout (bytes)
#define A_OFF 0u
#define B_OFF 17825792u                 // 2048*4352*2

typedef __bf16 bf16x8 __attribute__((ext_vector_type(8)));
typedef float f32x4 __attribute__((ext_vector_type(4)));

__device__ __forceinline__ unsigned short f32_to_bf16(float f) {
    unsigned u = __float_as_uint(f);
    u += 0x7FFFu + ((u >> 16) & 1u);     // round-to-nearest-even
    return (unsigned short)(u >> 16);
}

__device__ __forceinline__ float sigm_(float x) { return 1.f / (1.f + __expf(-x)); }
__device__ __forceinline__ float tanh_(float x) {
    x = fminf(15.f, fmaxf(-15.f, x));
    float e = __expf(2.f * x);
    return (e - 1.f) / (e + 1.f);
}

// ---------------------------------------------------------------------------
// Kernel 1 (r0 version, unchanged): pack z -> A, W_all gate-interleaved -> B.
// ---------------------------------------------------------------------------
__global__ __launch_bounds__(256) void convert_kernel(
    const float* __restrict__ x, const float* __restrict__ pt,
    const float* __restrict__ pl,
    const float* __restrict__ Wi, const float* __restrict__ Wf,
    const float* __restrict__ Wo, const float* __restrict__ Ws,
    unsigned short* __restrict__ Abf, unsigned short* __restrict__ Bbf)
{
    const int row = blockIdx.x;                  // 0..6143
    const float* srow = nullptr;
    unsigned short* drow;
    if (row < M_DIM) {
        drow = Abf + (size_t)row * K_DIM;
    } else {
        int n = row - M_DIM;                      // 0..4095
        int g = n >> 10, h = n & 1023;
        const float* W = (g == 0) ? Wi : (g == 1) ? Wf : (g == 2) ? Wo : Ws;
        srow = W + (size_t)h * K_DIM;
        drow = Bbf + (size_t)(h * 4 + g) * K_DIM;
    }

    for (int c8 = threadIdx.x; c8 < K_DIM / 8; c8 += 256) {
        int col = c8 * 8;
        const float* s;
        if (row < M_DIM) {
            if (col < X_DIM)              s = x  + (size_t)row * X_DIM + col;
            else if (col < X_DIM + H_DIM) s = pt + (size_t)row * H_DIM + (col - X_DIM);
            else                          s = pl + (size_t)row * H_DIM + (col - X_DIM - H_DIM);
        } else {
            s = srow + col;
        }
        float4 v0 = ((const float4*)s)[0];
        float4 v1 = ((const float4*)s)[1];
        union { unsigned short h[8]; uint4 u; } r;
        r.h[0] = f32_to_bf16(v0.x); r.h[1] = f32_to_bf16(v0.y);
        r.h[2] = f32_to_bf16(v0.z); r.h[3] = f32_to_bf16(v0.w);
        r.h[4] = f32_to_bf16(v1.x); r.h[5] = f32_to_bf16(v1.y);
        r.h[6] = f32_to_bf16(v1.z); r.h[7] = f32_to_bf16(v1.w);
        *(uint4*)(drow + col) = r.u;
    }
}

// ---------------------------------------------------------------------------
// Kernel 2: fused GEMM + gates. Round-9 = r8 with two anti-phase levers:
//  (a) setprio REMOVED: at prio1 an MFMA-ing wave starves the co-resident
//      block's ds_read issue on the same SIMD, enforcing the in-phase lock
//      (r8 measured: LDS 1536 + MFMA 1242 = 2778 ~ 2740 cyc/tile, perfectly
//      serial). Prio-flat lets reads issue under the other block's MFMAs.
//  (b) second-sweep blocks (b>>8)&1 sleep ~384cy (half a quadrant phase) at
//      entry, seeding anti-phase alignment between the 2 blocks on each CU.
// Dataflow, accumulation order, barriers: byte-identical to r8 -> absmax
// must remain exactly 0.006835938 (race canary).
// ---------------------------------------------------------------------------
__global__ __launch_bounds__(256, 2) void gemm_fused(
    const unsigned short* __restrict__ A,   // [M_DIM, K_DIM] bf16
    const unsigned short* __restrict__ B,   // [N_DIM, K_DIM] bf16, gate-interleaved
    const float* __restrict__ old_state,    // [2048, 1024]
    const float* __restrict__ bi, const float* __restrict__ bfv,
    const float* __restrict__ bo, const float* __restrict__ bs,
    float* __restrict__ out)                // [2048, 1024]
{
    // buf c at c*32768: sA [128 rows][8 kslots][16B] = 16 KB, sB at +16384.
    // Total 64 KB (2 blocks/CU = 128 KB of 160). sP (128*76*4) aliases buf0+.
    __shared__ __align__(16) char smem[65536];
    float* sP = (float*)smem;

    const int tid  = threadIdx.x;
    const int lane = tid & 63;
    const int wave = tid >> 6;              // 0..3
    const int wm = (wave >> 1) * 64;
    const int wn = (wave & 1) * 64;

    // XCD-aware decode (r0): xcd b&7 owns n-tiles 4*xcd..4*xcd+3
    const int b   = blockIdx.x;             // 0..511
    const int xcd = b & 7;
    const int j   = b >> 3;                 // 0..63
    const int n0  = (xcd * 4 + (j & 3)) * 128;
    const int m0  = (j >> 2) * 128;

    // anti-phase seed: second-sweep co-resident block starts ~384cy late
    if ((b >> 8) & 1) __builtin_amdgcn_s_sleep(6);

    // staging (r0): lane deposits 16B at slot (i*256 + wave*64 + lane);
    // logical row = i*32 + wave*8 + (lane>>3); pre-swizzled source col:
    const int srow = wave * 8 + (lane >> 3);
    const int c8s  = ((lane & 7) ^ (lane >> 3)) * 8;
    const unsigned short* Aw = A + (size_t)(m0 + srow) * K_DIM + c8s;
    const unsigned short* Bw = B + (size_t)(n0 + srow) * K_DIM + c8s;

    // fragment reads: row = w? + i*16 + fr; k-block kb = kh*4+kb0;
    // slot = kb ^ (fr&7); row stride 128 B
    const int fr  = lane & 15;
    const int kb0 = lane >> 4;              // 0..3
    const int sw  = fr & 7;
    const int sK0 = ((kb0    ) ^ sw) * 16;
    const int sK1 = ((kb0 ^ 4) ^ sw) * 16;
    const int aRow =         (wm + fr) * 128;   // + i*2048
    const int bRow = 16384 + (wn + fr) * 128;   // + j*2048

    f32x4 acc[4][4];
#pragma unroll
    for (int i = 0; i < 4; ++i)
#pragma unroll
        for (int jj = 0; jj < 4; ++jj) acc[i][jj] = (f32x4){0.f, 0.f, 0.f, 0.f};

    bf16x8 aF[4], bF[4], bG[4];             // A frags, B k-half0 bank, B k-half1 bank

#define GLDS(GP, LP) __builtin_amdgcn_global_load_lds(                          \
        (const __attribute__((address_space(1))) unsigned*)(GP),                \
        (__attribute__((address_space(3))) unsigned*)(LP), 16, 0, 0)

    auto STAGE_A = [&](int kt, int bufOff) {    // 4 loads: A rows 0..127, K64
#pragma unroll
        for (int i = 0; i < 4; ++i)
            GLDS(Aw + (size_t)i * 32 * K_DIM + kt,
                 smem + bufOff + i * 4096 + wave * 1024);
    };
    auto STAGE_B = [&](int kt, int bufOff) {    // 4 loads: B rows 0..127, K64
#pragma unroll
        for (int i = 0; i < 4; ++i)
            GLDS(Bw + (size_t)i * 32 * K_DIM + kt,
                 smem + bufOff + 16384 + i * 4096 + wave * 1024);
    };

#define RD_Q0(BUF) {                                                            \
        const char* bb_ = smem + (BUF);                                         \
        aF[0] = *(const bf16x8*)(bb_ + aRow + 0 * 2048 + sK0);                  \
        aF[1] = *(const bf16x8*)(bb_ + aRow + 1 * 2048 + sK0);                  \
        bF[0] = *(const bf16x8*)(bb_ + bRow + 0 * 2048 + sK0);                  \
        bF[1] = *(const bf16x8*)(bb_ + bRow + 1 * 2048 + sK0); }
#define RD_Q1(BUF) {                                                            \
        const char* bb_ = smem + (BUF);                                         \
        aF[2] = *(const bf16x8*)(bb_ + aRow + 2 * 2048 + sK0);                  \
        aF[3] = *(const bf16x8*)(bb_ + aRow + 3 * 2048 + sK0);                  \
        bF[2] = *(const bf16x8*)(bb_ + bRow + 2 * 2048 + sK0);                  \
        bF[3] = *(const bf16x8*)(bb_ + bRow + 3 * 2048 + sK0); }
#define RD_Q2(BUF) {                                                            \
        const char* bb_ = smem + (BUF);                                         \
        aF[0] = *(const bf16x8*)(bb_ + aRow + 0 * 2048 + sK1);                  \
        aF[1] = *(const bf16x8*)(bb_ + aRow + 1 * 2048 + sK1);                  \
        bG[0] = *(const bf16x8*)(bb_ + bRow + 0 * 2048 + sK1);                  \
        bG[1] = *(const bf16x8*)(bb_ + bRow + 1 * 2048 + sK1); }
#define RD_Q3(BUF) {                                                            \
        const char* bb_ = smem + (BUF);                                         \
        aF[2] = *(const bf16x8*)(bb_ + aRow + 2 * 2048 + sK1);                  \
        aF[3] = *(const bf16x8*)(bb_ + aRow + 3 * 2048 + sK1);                  \
        bG[2] = *(const bf16x8*)(bb_ + bRow + 2 * 2048 + sK1);                  \
        bG[3] = *(const bf16x8*)(bb_ + bRow + 3 * 2048 + sK1); }

#define MM_Q0                                                                   \
    _Pragma("unroll")                                                           \
    for (int j_ = 0; j_ < 4; ++j_) {                                            \
        acc[0][j_] = __builtin_amdgcn_mfma_f32_16x16x32_bf16(aF[0], bF[j_], acc[0][j_], 0, 0, 0); \
        acc[1][j_] = __builtin_amdgcn_mfma_f32_16x16x32_bf16(aF[1], bF[j_], acc[1][j_], 0, 0, 0); }
#define MM_Q1                                                                   \
    _Pragma("unroll")                                                           \
    for (int j_ = 0; j_ < 4; ++j_) {                                            \
        acc[2][j_] = __builtin_amdgcn_mfma_f32_16x16x32_bf16(aF[2], bF[j_], acc[2][j_], 0, 0, 0); \
        acc[3][j_] = __builtin_amdgcn_mfma_f32_16x16x32_bf16(aF[3], bF[j_], acc[3][j_], 0, 0, 0); }
#define MM_Q2                                                                   \
    _Pragma("unroll")                                                           \
    for (int j_ = 0; j_ < 4; ++j_) {                                            \
        acc[0][j_] = __builtin_amdgcn_mfma_f32_16x16x32_bf16(aF[0], bG[j_], acc[0][j_], 0, 0, 0); \
        acc[1][j_] = __builtin_amdgcn_mfma_f32_16x16x32_bf16(aF[1], bG[j_], acc[1][j_], 0, 0, 0); }
#define MM_Q3                                                                   \
    _Pragma("unroll")                                                           \
    for (int j_ = 0; j_ < 4; ++j_) {                                            \
        acc[2][j_] = __builtin_amdgcn_mfma_f32_16x16x32_bf16(aF[2], bG[j_], acc[2][j_], 0, 0, 0); \
        acc[3][j_] = __builtin_amdgcn_mfma_f32_16x16x32_bf16(aF[3], bG[j_], acc[3][j_], 0, 0, 0); }

#define VM0 asm volatile("s_waitcnt vmcnt(0)" ::: "memory")

    // single-barrier phase: reads+stage pinned before the barrier; MFMA after
    // (prio-flat). Next phase's reads drain under these MFMAs.
#define PH(RDLINE, STLINE, MMLINE)                                              \
    do {                                                                        \
        RDLINE; STLINE;                                                         \
        __builtin_amdgcn_sched_barrier(0);                                      \
        __builtin_amdgcn_s_barrier();                                           \
        MMLINE;                                                                 \
    } while (0)

    // tile computing from buffer CB; stages next tile (kt KTN) into CNB.
    // p3: vmcnt(0) drains this tile's 8 stage loads (only outstanding VMEM),
    // barrier, then read next tile's Q0 from the freshly staged buffer.
#define TILE(CB, CNB, KTN, DOST, DORD)                                          \
    PH(RD_Q1(CB), if (DOST) STAGE_A((KTN), (CNB)), MM_Q0);                      \
    PH(RD_Q2(CB), if (DOST) STAGE_B((KTN), (CNB)), MM_Q1);                      \
    PH(RD_Q3(CB), (void)0,                         MM_Q2);                      \
    do {                                                                        \
        if (DOST) VM0;                                                          \
        __builtin_amdgcn_sched_barrier(0);                                      \
        __builtin_amdgcn_s_barrier();                                           \
        if (DORD) RD_Q0(CNB);                                                   \
        MM_Q3;                                                                  \
    } while (0);

    // prologue: stage tile 0 into buf0; drain; read Q0.
    STAGE_A(0, 0); STAGE_B(0, 0);
    VM0;
    __builtin_amdgcn_s_barrier();
    RD_Q0(0);

    // 68 K64-tiles. Loop covers t=0..65 (33 iters x 2 tiles); peel 66, 67.
    for (int kt = 0; kt < 4224; kt += 128) {
        TILE(0,     32768, kt + 64,  true, true);
        TILE(32768, 0,     kt + 128, true, true);
    }
    TILE(0,     32768, 4288, true,  true);   // t=66: stage last tile
    TILE(32768, 0,     0,    false, false);  // t=67

#undef TILE
#undef PH
#undef VM0
#undef MM_Q0
#undef MM_Q1
#undef MM_Q2
#undef MM_Q3
#undef RD_Q0
#undef RD_Q1
#undef RD_Q2
#undef RD_Q3
#undef GLDS

    // ---- fused epilogue (r0 version): two half-passes over n -------------
    // C/D layout: col = lane&15, row = (lane>>4)*4 + reg
    const int cw = lane & 15;
    const int rw = (lane >> 4) * 4;
    const int hl = tid & 15;                // h within pass
    const int rb = tid >> 4;                // 0..15

    for (int p = 0; p < 2; ++p) {
        __syncthreads();                    // K-loop readers / pass p-1 done
        if ((wave & 1) == p) {              // waves owning n-half p write
#pragma unroll
            for (int i = 0; i < 4; ++i)
#pragma unroll
                for (int jj = 0; jj < 4; ++jj)
#pragma unroll
                    for (int r = 0; r < 4; ++r)
                        sP[(wm + i * 16 + rw + r) * 76 + jj * 16 + cw] = acc[i][jj][r];
        }
        __syncthreads();                    // sP populated

        const int hg = (n0 >> 2) + p * 16 + hl;   // global hidden index
        const float b_i = bi[hg], b_f = bfv[hg], b_o = bo[hg], b_s = bs[hg];
#pragma unroll
        for (int k = 0; k < 8; ++k) {
            const int row = rb + 16 * k;          // 0..127
            float4 g = *(const float4*)(sP + row * 76 + hl * 4);
            const size_t oidx = (size_t)(m0 + row) * H_DIM + hg;
            float old = old_state[oidx];
            float ig = sigm_(g.x + b_i);
            float fg = sigm_(g.y + b_f);
            float og = sigm_(g.z + b_o);
            float ts = tanh_(g.w + b_s);
            out[oidx] = og * tanh_(fg * old + ig * ts);
        }
    }
}

// ---------------------------------------------------------------------------
extern "C" void kernel_launch(void* const* d_in, const int* in_sizes, int n_in,
                              void* d_out, int out_size, void* d_ws, size_t ws_size,
                              hipStream_t stream) {
    const float* x   = (const float*)d_in[0];
    const float* pt  = (const float*)d_in[1];
    const float* pl  = (const float*)d_in[2];
    const float* old = (const float*)d_in[3];
    const float* Wi  = (const float*)d_in[4];
    const float* bi  = (const float*)d_in[5];
    const float* Wf  = (const float*)d_in[6];
    const float* bf  = (const float*)d_in[7];
    const float* Wo  = (const float*)d_in[8];
    const float* bo  = (const float*)d_in[9];
    const float* Ws  = (const float*)d_in[10];
    const float* bs  = (const float*)d_in[11];
    float* out = (float*)d_out;

    char* ws = (char*)d_ws;
    unsigned short* Abf = (unsigned short*)(ws + A_OFF);
    unsigned short* Bbf = (unsigned short*)(ws + B_OFF);

    // 1) pack/convert: one block per destination row
    convert_kernel<<<M_DIM + N_DIM, 256, 0, stream>>>(x, pt, pl, Wi, Wf, Wo, Ws, Abf, Bbf);

    // 2) fused GEMM + gates, XCD-swizzled grid, 2 blocks/CU
    gemm_fused<<<512, 256, 0, stream>>>(Abf, Bbf, old, bi, bf, bo, bs, out);
}